// Round 4
// baseline (391.021 us; speedup 1.0000x reference)
//
#include <hip/hip_runtime.h>
#include <hip/hip_bf16.h>

typedef _Float16 half8  __attribute__((ext_vector_type(8)));
typedef _Float16 half4v __attribute__((ext_vector_type(4)));
typedef float    f32x4  __attribute__((ext_vector_type(4)));

#define N_NODES 100000
#define N_EDGES 3200000
#define SH_STRIDE 100096   // fallback shadow stride (floats)
#define NBUCK 782          // 128 nodes per bucket == one sage tile
#define CAP   5120         // records/bucket: mean 4092 + 16 sigma
#define CHUNK 4096         // edges per bin block (512 thr x 2 x int4)
#define NBIN  782          // ceil(N_EDGES/CHUNK)
#define NPK   32           // pack blocks appended to bin grid

// ---------------------------------------------------------------------------
// Bin + pack kernel (R2 version, measured neutral vs R0 original -> keep).
// R2 post-mortem: binpack is NOT the gap -- the ~126-139 us total-minus-sage
// gap is dominated by ~122 harness reset dispatches per iteration. Do not
// spend rounds here.
// ---------------------------------------------------------------------------
__global__ __launch_bounds__(512) void binpack(
    const float* __restrict__ ef, const int* __restrict__ dst,
    const float* __restrict__ W1,  const float* __restrict__ Wm1,
    const float* __restrict__ Wm2, const float* __restrict__ Wm3,
    const float* __restrict__ Wm4, const float* __restrict__ Wr1,
    const float* __restrict__ Wr2,
    const float* __restrict__ b1,  const float* __restrict__ bm1,
    const float* __restrict__ bm2, const float* __restrict__ bm3,
    const float* __restrict__ bm4, const float* __restrict__ br1,
    const float* __restrict__ br2, const float* __restrict__ wr3,
    const float* __restrict__ br3,
    int* __restrict__ cursor, unsigned* __restrict__ pairs,
    _Float16* __restrict__ Wp, float* __restrict__ park, int do_bin) {

    if (do_bin && blockIdx.x < NBIN) {
        __shared__ int      hist[NBUCK];
        __shared__ int      base[NBUCK];   // absolute global base per bucket
        __shared__ int      lbase[NBUCK];  // LDS group base per bucket
        __shared__ int      wsum[8];       // per-wave scan totals
        __shared__ unsigned lrec[CHUNK];   // grouped records
        __shared__ int      lslot[CHUNK];  // grouped global slots (-1 = drop)
        const int start = blockIdx.x * CHUNK;
        const int tid   = threadIdx.x;
        const int wave  = tid >> 6;
        const int lane  = tid & 63;
        for (int b = tid; b < NBUCK; b += 512) hist[b] = 0;
        __syncthreads();

        // phase1: histogram; keep each edge's rank in registers
        int4   dreg[2];
        float4 freg[2];
        int    rnk[2][4];
        #pragma unroll
        for (int it = 0; it < 2; ++it) {
            const int i = start + (it * 512 + tid) * 4;
            if (i < N_EDGES) {
                dreg[it] = *(const int4*)&dst[i];
                freg[it] = *(const float4*)&ef[i];
                rnk[it][0] = atomicAdd(&hist[dreg[it].x >> 7], 1);
                rnk[it][1] = atomicAdd(&hist[dreg[it].y >> 7], 1);
                rnk[it][2] = atomicAdd(&hist[dreg[it].z >> 7], 1);
                rnk[it][3] = atomicAdd(&hist[dreg[it].w >> 7], 1);
            }
        }
        __syncthreads();

        // reserve global space (one atomic per nonzero bucket)
        for (int b = tid; b < NBUCK; b += 512) {
            const int c = hist[b];
            base[b] = b * CAP + ((c > 0) ? atomicAdd(&cursor[b], c) : 0);
        }
        // scan: thread owns buckets 2t, 2t+1; wave shfl prefix + fixup
        const int b0 = 2 * tid, b1 = 2 * tid + 1;
        const int h0 = (b0 < NBUCK) ? hist[b0] : 0;
        const int h1 = (b1 < NBUCK) ? hist[b1] : 0;
        const int psum = h0 + h1;
        int pfx = psum;
        #pragma unroll
        for (int ofs = 1; ofs < 64; ofs <<= 1) {
            const int v = __shfl_up(pfx, ofs);
            if (lane >= ofs) pfx += v;
        }
        if (lane == 63) wsum[wave] = pfx;
        __syncthreads();
        int woff = 0;
        #pragma unroll
        for (int w = 0; w < 8; ++w) woff += (w < wave) ? wsum[w] : 0;
        const int excl = woff + pfx - psum;   // exclusive prefix of bucket b0
        if (b0 < NBUCK) lbase[b0] = excl;
        if (b1 < NBUCK) lbase[b1] = excl + h0;
        __syncthreads();

        // phase2: place into LDS grouped by bucket (saved ranks, no atomics)
        #pragma unroll
        for (int it = 0; it < 2; ++it) {
            const int i = start + (it * 512 + tid) * 4;
            if (i < N_EDGES) {
                const int4   d = dreg[it];
                const float4 f = freg[it];
                {   const int bk = d.x >> 7; const int r = rnk[it][0];
                    const int s = lbase[bk] + r; const int g = base[bk] + r;
                    lrec[s]  = (__float_as_uint(f.x) & 0xFFFFFF00u) | (unsigned)(d.x & 127);
                    lslot[s] = (g < (bk + 1) * CAP) ? g : -1; }
                {   const int bk = d.y >> 7; const int r = rnk[it][1];
                    const int s = lbase[bk] + r; const int g = base[bk] + r;
                    lrec[s]  = (__float_as_uint(f.y) & 0xFFFFFF00u) | (unsigned)(d.y & 127);
                    lslot[s] = (g < (bk + 1) * CAP) ? g : -1; }
                {   const int bk = d.z >> 7; const int r = rnk[it][2];
                    const int s = lbase[bk] + r; const int g = base[bk] + r;
                    lrec[s]  = (__float_as_uint(f.z) & 0xFFFFFF00u) | (unsigned)(d.z & 127);
                    lslot[s] = (g < (bk + 1) * CAP) ? g : -1; }
                {   const int bk = d.w >> 7; const int r = rnk[it][3];
                    const int s = lbase[bk] + r; const int g = base[bk] + r;
                    lrec[s]  = (__float_as_uint(f.w) & 0xFFFFFF00u) | (unsigned)(d.w & 127);
                    lslot[s] = (g < (bk + 1) * CAP) ? g : -1; }
            }
        }
        __syncthreads();
        // phase3: coalesced run writes
        const int total = min(CHUNK, N_EDGES - start);
        for (int s = tid; s < total; s += 512) {
            const int g = lslot[s];
            if (g >= 0) pairs[g] = lrec[s];
        }
    } else {
        const float* srcs[7] = {W1, Wm1, Wm2, Wm3, Wm4, Wr1, Wr2};
        const float* bias[7] = {b1, bm1, bm2, bm3, bm4, br1, br2};
        const int pb  = do_bin ? ((int)blockIdx.x - NBIN) : (int)blockIdx.x;
        const int gid = pb * 512 + threadIdx.x;
        const int gsz = NPK * 512;
        for (int i = gid; i < 425984; i += gsz) {
            int job, row, k, stride;
            if (i < 32768) { job = 0; row = i >> 7; k = i & 127; stride = 129; }
            else {
                int t = i - 32768; job = 1 + (t >> 16); int w = t & 65535;
                row = w >> 8; k = w & 255; stride = (job == 6) ? 256 : 257;
            }
            Wp[i] = (_Float16)srcs[job][row * stride + k];
        }
        for (int i = gid; i < 1536; i += gsz) {
            const int job = i >> 8, row = i & 255;
            const int stride = (job == 0) ? 129 : 257;
            const int kin    = (job == 0) ? 128 : 256;
            park[job * 512 + row] = srcs[job][row * stride + kin];
        }
        for (int i = gid; i < 256; i += gsz) park[6 * 512 + i] = 0.f;
        for (int i = gid; i < 1792; i += gsz)
            park[(i >> 8) * 512 + 256 + (i & 255)] = bias[i >> 8][i & 255];
        for (int i = gid; i < 256; i += gsz) park[3584 + i] = wr3[i];
        if (gid == 0) park[3840] = br3[0];
    }
}

// fallback: device-scope split-4 scatter (known-good)
__global__ void scatter4(const float4* __restrict__ ef4,
                         const int4* __restrict__ dst4,
                         float* __restrict__ e) {
    const int n4 = N_EDGES / 4;
    for (int i = blockIdx.x * blockDim.x + threadIdx.x; i < n4;
         i += gridDim.x * blockDim.x) {
        const float4 f = ef4[i];
        const int4   d = dst4[i];
        atomicAdd(&e[d.x], f.x);
        atomicAdd(&e[SH_STRIDE + d.y], f.y);
        atomicAdd(&e[2 * SH_STRIDE + d.z], f.z);
        atomicAdd(&e[3 * SH_STRIDE + d.w], f.w);
    }
}

// ---------------------------------------------------------------------------
// R4: node-dim TIME-SPLIT layer. Wave still owns 64 output cols x 128 nodes
// (same wave grid, same occupancy, same per-CU traffic as the proven R0
// shape) but processes nodes in two passes of 64: acc[4][4] = 64 VGPR
// instead of acc[4][8] = 128. Rationale: at the 128-VGPR cap, acc alone
// filled the budget, so a/b-frags + addresses + park constants round-tripped
// through scratch (L1/L2, ~200cy) inside EVERY kstep -- the suspected source
// of the 120 us of non-MFMA wall. Park epilogue constants now load AFTER the
// MFMA loop (they were 32 loop-live regs). a-frags are re-read once per pass
// from L2 (cheap); b-read totals unchanged.
// Barrier structure (3/layer, race-free):
//   pass0 MFMA (reads rows 0-63) -> sync -> pass0 write rows 0-63
//   pass1 MFMA (reads rows 64-127: disjoint from pass0 writes, no sync
//   needed between) -> sync -> pass1 write rows 64-127 -> sync
// ---------------------------------------------------------------------------
template<int K>
__device__ __forceinline__ void layer_mm(const _Float16* __restrict__ Wl,
                                         _Float16 (* __restrict__ Hs)[264],
                                         const float* __restrict__ es,
                                         const float* __restrict__ parkl,
                                         int wave, int m_, int quad) {
    const int jb0 = wave * 64 + quad * 4;
    const _Float16* __restrict__ wp = Wl + (size_t)(wave * 64 + m_) * K + quad * 8;

    for (int mp = 0; mp < 2; ++mp) {
        const int row0 = mp * 64;

        f32x4 acc[4][4];
        #pragma unroll
        for (int jt = 0; jt < 4; ++jt)
            #pragma unroll
            for (int mt = 0; mt < 4; ++mt)
                acc[jt][mt] = (f32x4){0.f, 0.f, 0.f, 0.f};

        half8 a[4];
        #pragma unroll
        for (int jt = 0; jt < 4; ++jt)
            a[jt] = *(const half8*)(wp + jt * 16 * K);

        #pragma unroll
        for (int kk = 0; kk < K; kk += 32) {
            half8 a2[4];
            if (kk + 32 < K) {
                #pragma unroll
                for (int jt = 0; jt < 4; ++jt)
                    a2[jt] = *(const half8*)(wp + jt * 16 * K + kk + 32);
            }
            half8 b[4];
            #pragma unroll
            for (int mt = 0; mt < 4; ++mt)
                b[mt] = *(const half8*)&Hs[row0 + mt * 16 + m_][kk + quad * 8];
            #pragma unroll
            for (int jt = 0; jt < 4; ++jt)
                #pragma unroll
                for (int mt = 0; mt < 4; ++mt)
                    acc[jt][mt] = __builtin_amdgcn_mfma_f32_16x16x32_f16(
                        a[jt], b[mt], acc[jt][mt], 0, 0, 0);
            if (kk + 32 < K) {
                #pragma unroll
                for (int jt = 0; jt < 4; ++jt) a[jt] = a2[jt];
            }
        }
        __syncthreads();   // all waves done reading this pass's rows

        // epilogue constants AFTER the loop: not loop-live, no spill pressure
        float4 w4[4], bb[4];
        #pragma unroll
        for (int jt = 0; jt < 4; ++jt) {
            w4[jt] = *(const float4*)&parkl[jt * 16 + jb0];
            bb[jt] = *(const float4*)&parkl[256 + jt * 16 + jb0];
        }

        #pragma unroll
        for (int jt = 0; jt < 4; ++jt) {
            const int jbase = jb0 + jt * 16;
            #pragma unroll
            for (int mt = 0; mt < 4; ++mt) {
                const int node = row0 + mt * 16 + m_;
                const float ev = es[node];
                half4v h;
                h[0] = (_Float16)fmaxf(acc[jt][mt][0] + ev * w4[jt].x + bb[jt].x, 0.f);
                h[1] = (_Float16)fmaxf(acc[jt][mt][1] + ev * w4[jt].y + bb[jt].y, 0.f);
                h[2] = (_Float16)fmaxf(acc[jt][mt][2] + ev * w4[jt].z + bb[jt].z, 0.f);
                h[3] = (_Float16)fmaxf(acc[jt][mt][3] + ev * w4[jt].w + bb[jt].w, 0.f);
                *(half4v*)&Hs[node][jbase] = h;
            }
        }
        // pass1 MFMA reads rows 64-127 only -> pass0's writes (rows 0-63)
        // need no barrier before it; final sync below covers visibility.
    }
    __syncthreads();   // all Hs writes visible before next layer
}

// ---------------------------------------------------------------------------
// (256,2) kept: caps VGPR at 128. R4 makes the K-loop FIT the cap (acc 64 +
// a 16 + a2 16 + b 16 + addresses) instead of "living with" the spill.
// History: R0 4-wave acc128 + spill = 159-170 us; R1 8-wave acc64 = 242 us
// (confounded: halved per-wave work AND doubled per-CU W streams); clean
// VGPR-160 = 203-207 us. R4 isolates the spill variable at fixed occupancy.
__global__ __launch_bounds__(256, 2) void sage_fused(
    const float* __restrict__ node_feat,
    const int* __restrict__ cursor, const unsigned* __restrict__ pairs,
    const float* __restrict__ esh, int nsh,
    const _Float16* __restrict__ Wpack, const float* __restrict__ park,
    float* __restrict__ out) {

    __shared__ _Float16 Hs[128][264];   // +8-half pad
    __shared__ float esp[528];          // 4 shadows @ stride 132 (bank 4s+n)
    __shared__ float es[128];           // combined aggregate
    __shared__ float wf[256];
    __shared__ float red[2][128];

    const int tid  = threadIdx.x;
    const int wave = tid >> 6;
    const int lane = tid & 63;
    const int m_   = lane & 15;
    const int quad = lane >> 4;
    const int node0 = blockIdx.x * 128;

    for (int i = tid; i < 528; i += 256) esp[i] = 0.f;

    // hoist the gating cursor load: latency hides under the staging loop
    int cnt = 0;
    if (nsh == 0) cnt = min(cursor[blockIdx.x], CAP);
    __syncthreads();

    // ---- stage node_feat tile (fp32 -> fp16) ----
    for (int idx = tid; idx < 128 * 16; idx += 256) {
        const int row = idx >> 4, g = idx & 15;
        int node = node0 + row; if (node >= N_NODES) node = N_NODES - 1;
        const float4* src = (const float4*)(node_feat + (size_t)node * 128 + g * 8);
        const float4 v0 = src[0], v1 = src[1];
        half8 h;
        h[0] = (_Float16)v0.x; h[1] = (_Float16)v0.y;
        h[2] = (_Float16)v0.z; h[3] = (_Float16)v0.w;
        h[4] = (_Float16)v1.x; h[5] = (_Float16)v1.y;
        h[6] = (_Float16)v1.z; h[7] = (_Float16)v1.w;
        *(half8*)&Hs[row][g * 8] = h;
    }
    // ---- edge aggregate for this 128-node tile (1:1 bucket) ----
    if (nsh == 0) {
        const unsigned* __restrict__ pp = pairs + (size_t)blockIdx.x * CAP;
        const int sh = (tid & 3) * 132;
        for (int i = tid; i < cnt; i += 256) {
            const unsigned p = pp[i];
            atomicAdd(&esp[sh + (p & 127u)], __uint_as_float(p & 0xFFFFFF00u));
        }
    } else if (tid < 128) {
        int node = node0 + tid; if (node >= N_NODES) node = N_NODES - 1;
        float s = 0.f;
        for (int sh = 0; sh < nsh; ++sh) s += esh[(size_t)sh * SH_STRIDE + node];
        esp[tid] = s;
    }
    __syncthreads();
    if (tid < 128)
        es[tid] = esp[tid] + esp[132 + tid] + esp[264 + tid] + esp[396 + tid];
    __syncthreads();

    // layer 0: K=128; layers 1..6: K=256 (in-place Hs, 3 barriers each)
    layer_mm<128>(Wpack, Hs, es, park, wave, m_, quad);
    for (int l = 1; l < 7; ++l)
        layer_mm<256>(Wpack + 32768 + (l - 1) * 65536, Hs, es, park + l * 512,
                      wave, m_, quad);

    // ---- final 256 -> 1 dot (fp32, b128-vectorized LDS reads) ----
    wf[tid] = park[3584 + tid];
    __syncthreads();
    {
        const int row = tid & 127, seg = tid >> 7;
        const _Float16* hp = &Hs[row][seg * 128];
        const float* wpt = &wf[seg * 128];
        float s = 0.f;
        #pragma unroll
        for (int k = 0; k < 16; ++k) {
            const half8 h = *(const half8*)(hp + k * 8);
            const float* w8 = wpt + k * 8;
            s += (float)h[0] * w8[0] + (float)h[1] * w8[1]
               + (float)h[2] * w8[2] + (float)h[3] * w8[3]
               + (float)h[4] * w8[4] + (float)h[5] * w8[5]
               + (float)h[6] * w8[6] + (float)h[7] * w8[7];
        }
        red[seg][row] = s;
    }
    __syncthreads();
    if (tid < 128) {
        const int node = node0 + tid;
        if (node < N_NODES)
            out[node] = red[0][tid] + red[1][tid] + park[3840];
    }
}

// ---------------------------------------------------------------------------
extern "C" void kernel_launch(void* const* d_in, const int* in_sizes, int n_in,
                              void* d_out, int out_size, void* d_ws,
                              size_t ws_size, hipStream_t stream) {
    const float* node_feat = (const float*)d_in[0];
    const float* edge_feat = (const float*)d_in[1];
    const int*   edge_dst  = (const int*)d_in[2];
    const float* W1  = (const float*)d_in[3];  const float* b1  = (const float*)d_in[4];
    const float* Wm1 = (const float*)d_in[5];  const float* bm1 = (const float*)d_in[6];
    const float* Wm2 = (const float*)d_in[7];  const float* bm2 = (const float*)d_in[8];
    const float* Wm3 = (const float*)d_in[9];  const float* bm3 = (const float*)d_in[10];
    const float* Wm4 = (const float*)d_in[11]; const float* bm4 = (const float*)d_in[12];
    const float* Wr1 = (const float*)d_in[13]; const float* br1 = (const float*)d_in[14];
    const float* Wr2 = (const float*)d_in[15]; const float* br2 = (const float*)d_in[16];
    const float* Wr3 = (const float*)d_in[17]; const float* br3 = (const float*)d_in[18];
    float* out = (float*)d_out;

    // ws layout: cursor | Wp | park | pairs (fallback: esh over pairs)
    char* ws = (char*)d_ws;
    int*      cursor = (int*)ws;                           // 4096 B reserved
    _Float16* Wp     = (_Float16*)(ws + 4096);             // 851968 B
    float*    park   = (float*)(ws + 856064);              // 16384 B
    unsigned* pairs  = (unsigned*)(ws + 872448);           // NBUCK*CAP*4 B
    float*    esh    = (float*)(ws + 872448);              // fallback shadows

    const size_t need_bins = 872448 + (size_t)NBUCK * CAP * 4;   // ~16.9 MB
    const bool use_bins = (ws_size >= need_bins);

    const int nblk = (N_NODES + 127) / 128;   // 782

    if (use_bins) {
        hipMemsetAsync(cursor, 0, NBUCK * sizeof(int), stream);
        binpack<<<NBIN + NPK, 512, 0, stream>>>(
            edge_feat, edge_dst, W1, Wm1, Wm2, Wm3, Wm4, Wr1, Wr2,
            b1, bm1, bm2, bm3, bm4, br1, br2, Wr3, br3,
            cursor, pairs, Wp, park, 1);
        sage_fused<<<nblk, 256, 0, stream>>>(node_feat, cursor, pairs,
                                             nullptr, 0, Wp, park, out);
    } else {
        binpack<<<NPK, 512, 0, stream>>>(
            edge_feat, edge_dst, W1, Wm1, Wm2, Wm3, Wm4, Wr1, Wr2,
            b1, bm1, bm2, bm3, bm4, br1, br2, Wr3, br3,
            cursor, pairs, Wp, park, 0);
        hipMemsetAsync(esh, 0, (size_t)4 * SH_STRIDE * 4, stream);
        scatter4<<<3125, 256, 0, stream>>>((const float4*)edge_feat,
                                           (const int4*)edge_dst, esh);
        sage_fused<<<nblk, 256, 0, stream>>>(node_feat, nullptr, nullptr,
                                             esh, 4, Wp, park, out);
    }
}

// Round 5
// 277.185 us; speedup vs baseline: 1.4107x; 1.4107x over previous
//
#include <hip/hip_runtime.h>
#include <hip/hip_bf16.h>

typedef _Float16 half8  __attribute__((ext_vector_type(8)));
typedef _Float16 half4v __attribute__((ext_vector_type(4)));
typedef float    f32x4  __attribute__((ext_vector_type(4)));

#define N_NODES 100000
#define N_EDGES 3200000
#define SH_STRIDE 100096   // fallback shadow stride (floats)
#define NBUCK 782          // 128 nodes per bucket == one sage tile
#define CAP   5120         // records/bucket: mean 4092 + 16 sigma
#define CHUNK 4096         // edges per bin block (512 thr x 2 x int4)
#define NBIN  782          // ceil(N_EDGES/CHUNK)
#define NPK   32           // pack blocks appended to bin grid

// ---------------------------------------------------------------------------
// Bin + pack kernel. R5: the pack phase now writes Wp in MFMA-FRAGMENT-MAJOR
// order instead of row-major:
//   Wp[layer_off + w*64*K + (s*4 + j)*512 + lane*8 + e]
//     = W[w*64 + j*16 + (lane&15)][s*32 + (lane>>4)*8 + e]
// so each a-frag load in sage_fused is lane-contiguous (lane i reads
// base + i*16B -> ONE coalesced 1KB transaction). R4's F+c model showed
// ~2200 cyc of per-kstep fixed cost matching the old scattered loads
// (16 x 64B segments per instruction, ~64 VMEM txn/kstep/wave).
// Bin phase unchanged (R2 version, measured neutral; binpack is not the gap).
// ---------------------------------------------------------------------------
__global__ __launch_bounds__(512) void binpack(
    const float* __restrict__ ef, const int* __restrict__ dst,
    const float* __restrict__ W1,  const float* __restrict__ Wm1,
    const float* __restrict__ Wm2, const float* __restrict__ Wm3,
    const float* __restrict__ Wm4, const float* __restrict__ Wr1,
    const float* __restrict__ Wr2,
    const float* __restrict__ b1,  const float* __restrict__ bm1,
    const float* __restrict__ bm2, const float* __restrict__ bm3,
    const float* __restrict__ bm4, const float* __restrict__ br1,
    const float* __restrict__ br2, const float* __restrict__ wr3,
    const float* __restrict__ br3,
    int* __restrict__ cursor, unsigned* __restrict__ pairs,
    _Float16* __restrict__ Wp, float* __restrict__ park, int do_bin) {

    if (do_bin && blockIdx.x < NBIN) {
        __shared__ int      hist[NBUCK];
        __shared__ int      base[NBUCK];   // absolute global base per bucket
        __shared__ int      lbase[NBUCK];  // LDS group base per bucket
        __shared__ int      wsum[8];       // per-wave scan totals
        __shared__ unsigned lrec[CHUNK];   // grouped records
        __shared__ int      lslot[CHUNK];  // grouped global slots (-1 = drop)
        const int start = blockIdx.x * CHUNK;
        const int tid   = threadIdx.x;
        const int wave  = tid >> 6;
        const int lane  = tid & 63;
        for (int b = tid; b < NBUCK; b += 512) hist[b] = 0;
        __syncthreads();

        // phase1: histogram; keep each edge's rank in registers
        int4   dreg[2];
        float4 freg[2];
        int    rnk[2][4];
        #pragma unroll
        for (int it = 0; it < 2; ++it) {
            const int i = start + (it * 512 + tid) * 4;
            if (i < N_EDGES) {
                dreg[it] = *(const int4*)&dst[i];
                freg[it] = *(const float4*)&ef[i];
                rnk[it][0] = atomicAdd(&hist[dreg[it].x >> 7], 1);
                rnk[it][1] = atomicAdd(&hist[dreg[it].y >> 7], 1);
                rnk[it][2] = atomicAdd(&hist[dreg[it].z >> 7], 1);
                rnk[it][3] = atomicAdd(&hist[dreg[it].w >> 7], 1);
            }
        }
        __syncthreads();

        // reserve global space (one atomic per nonzero bucket)
        for (int b = tid; b < NBUCK; b += 512) {
            const int c = hist[b];
            base[b] = b * CAP + ((c > 0) ? atomicAdd(&cursor[b], c) : 0);
        }
        // scan: thread owns buckets 2t, 2t+1; wave shfl prefix + fixup
        const int b0 = 2 * tid, b1 = 2 * tid + 1;
        const int h0 = (b0 < NBUCK) ? hist[b0] : 0;
        const int h1 = (b1 < NBUCK) ? hist[b1] : 0;
        const int psum = h0 + h1;
        int pfx = psum;
        #pragma unroll
        for (int ofs = 1; ofs < 64; ofs <<= 1) {
            const int v = __shfl_up(pfx, ofs);
            if (lane >= ofs) pfx += v;
        }
        if (lane == 63) wsum[wave] = pfx;
        __syncthreads();
        int woff = 0;
        #pragma unroll
        for (int w = 0; w < 8; ++w) woff += (w < wave) ? wsum[w] : 0;
        const int excl = woff + pfx - psum;   // exclusive prefix of bucket b0
        if (b0 < NBUCK) lbase[b0] = excl;
        if (b1 < NBUCK) lbase[b1] = excl + h0;
        __syncthreads();

        // phase2: place into LDS grouped by bucket (saved ranks, no atomics)
        #pragma unroll
        for (int it = 0; it < 2; ++it) {
            const int i = start + (it * 512 + tid) * 4;
            if (i < N_EDGES) {
                const int4   d = dreg[it];
                const float4 f = freg[it];
                {   const int bk = d.x >> 7; const int r = rnk[it][0];
                    const int s = lbase[bk] + r; const int g = base[bk] + r;
                    lrec[s]  = (__float_as_uint(f.x) & 0xFFFFFF00u) | (unsigned)(d.x & 127);
                    lslot[s] = (g < (bk + 1) * CAP) ? g : -1; }
                {   const int bk = d.y >> 7; const int r = rnk[it][1];
                    const int s = lbase[bk] + r; const int g = base[bk] + r;
                    lrec[s]  = (__float_as_uint(f.y) & 0xFFFFFF00u) | (unsigned)(d.y & 127);
                    lslot[s] = (g < (bk + 1) * CAP) ? g : -1; }
                {   const int bk = d.z >> 7; const int r = rnk[it][2];
                    const int s = lbase[bk] + r; const int g = base[bk] + r;
                    lrec[s]  = (__float_as_uint(f.z) & 0xFFFFFF00u) | (unsigned)(d.z & 127);
                    lslot[s] = (g < (bk + 1) * CAP) ? g : -1; }
                {   const int bk = d.w >> 7; const int r = rnk[it][3];
                    const int s = lbase[bk] + r; const int g = base[bk] + r;
                    lrec[s]  = (__float_as_uint(f.w) & 0xFFFFFF00u) | (unsigned)(d.w & 127);
                    lslot[s] = (g < (bk + 1) * CAP) ? g : -1; }
            }
        }
        __syncthreads();
        // phase3: coalesced run writes
        const int total = min(CHUNK, N_EDGES - start);
        for (int s = tid; s < total; s += 512) {
            const int g = lslot[s];
            if (g >= 0) pairs[g] = lrec[s];
        }
    } else {
        const float* srcs[7] = {W1, Wm1, Wm2, Wm3, Wm4, Wr1, Wr2};
        const float* bias[7] = {b1, bm1, bm2, bm3, bm4, br1, br2};
        const int pb  = do_bin ? ((int)blockIdx.x - NBIN) : (int)blockIdx.x;
        const int gid = pb * 512 + threadIdx.x;
        const int gsz = NPK * 512;
        // fragment-major weight pack (see header comment)
        for (int i = gid; i < 425984; i += gsz) {
            int job, w, s, j, lane, e, stride;
            if (i < 32768) {            // layer 0, K=128 (4 ksteps/wave)
                job = 0; stride = 129;
                w = i >> 13;            // 8192 halfs per wave
                const int rem = i & 8191;
                s = rem >> 11;          // 2048 halfs per kstep
                j = (rem >> 9) & 3;
                lane = (rem >> 3) & 63;
                e = rem & 7;
            } else {                    // layers 1..6, K=256 (8 ksteps/wave)
                const int t = i - 32768;
                job = 1 + (t >> 16);
                const int local = t & 65535;
                stride = (job == 6) ? 256 : 257;
                w = local >> 14;        // 16384 halfs per wave
                const int rem = local & 16383;
                s = rem >> 11;
                j = (rem >> 9) & 3;
                lane = (rem >> 3) & 63;
                e = rem & 7;
            }
            const int row = w * 64 + j * 16 + (lane & 15);
            const int col = s * 32 + ((lane >> 4) << 3) + e;
            Wp[i] = (_Float16)srcs[job][row * stride + col];
        }
        for (int i = gid; i < 1536; i += gsz) {
            const int job = i >> 8, row = i & 255;
            const int stride = (job == 0) ? 129 : 257;
            const int kin    = (job == 0) ? 128 : 256;
            park[job * 512 + row] = srcs[job][row * stride + kin];
        }
        for (int i = gid; i < 256; i += gsz) park[6 * 512 + i] = 0.f;
        for (int i = gid; i < 1792; i += gsz)
            park[(i >> 8) * 512 + 256 + (i & 255)] = bias[i >> 8][i & 255];
        for (int i = gid; i < 256; i += gsz) park[3584 + i] = wr3[i];
        if (gid == 0) park[3840] = br3[0];
    }
}

// fallback: device-scope split-4 scatter (known-good)
__global__ void scatter4(const float4* __restrict__ ef4,
                         const int4* __restrict__ dst4,
                         float* __restrict__ e) {
    const int n4 = N_EDGES / 4;
    for (int i = blockIdx.x * blockDim.x + threadIdx.x; i < n4;
         i += gridDim.x * blockDim.x) {
        const float4 f = ef4[i];
        const int4   d = dst4[i];
        atomicAdd(&e[d.x], f.x);
        atomicAdd(&e[SH_STRIDE + d.y], f.y);
        atomicAdd(&e[2 * SH_STRIDE + d.z], f.z);
        atomicAdd(&e[3 * SH_STRIDE + d.w], f.w);
    }
}

// ---------------------------------------------------------------------------
// One layer over a 128-node tile. R0-proven shape (4 waves, acc[4][8],
// 2 barriers) -- R1 (8-wave) and R4 (time-split) both regressed badly;
// the F+c per-kstep model from those rounds fingered the SCATTERED a-loads
// (16 x 64B segments/instr) as the ~2200-cyc fixed cost. R5: Wp is now
// fragment-major, so a[jt] at kstep s is ONE lane-contiguous 1KB load at
// Wl + wave*64K + (s*4+jt)*512 + lane*8; the 4 loads per kstep are 4
// consecutive KBs (base reg + immediate offsets).
// ---------------------------------------------------------------------------
template<int K>
__device__ __forceinline__ void layer_mm(const _Float16* __restrict__ Wl,
                                         _Float16 (* __restrict__ Hs)[264],
                                         const float* __restrict__ es,
                                         const float* __restrict__ parkl,
                                         int wave, int lane, int m_, int quad) {
    f32x4 acc[4][8];
    #pragma unroll
    for (int jt = 0; jt < 4; ++jt)
        #pragma unroll
        for (int mt = 0; mt < 8; ++mt)
            acc[jt][mt] = (f32x4){0.f, 0.f, 0.f, 0.f};

    const int jb0 = wave * 64 + quad * 4;
    float4 w4[4], bb[4];
    #pragma unroll
    for (int jt = 0; jt < 4; ++jt) {
        w4[jt] = *(const float4*)&parkl[jt * 16 + jb0];
        bb[jt] = *(const float4*)&parkl[256 + jt * 16 + jb0];
    }

    // fragment-major: wave's whole-layer W slice is 64*K contiguous halfs
    const _Float16* __restrict__ wp = Wl + (size_t)wave * (64 * K) + lane * 8;

    half8 a[4];
    #pragma unroll
    for (int jt = 0; jt < 4; ++jt)
        a[jt] = *(const half8*)(wp + jt * 512);

    #pragma unroll
    for (int kk = 0; kk < K; kk += 32) {
        const int s = kk >> 5;
        half8 a2[4];
        if (kk + 32 < K) {
            #pragma unroll
            for (int jt = 0; jt < 4; ++jt)
                a2[jt] = *(const half8*)(wp + ((s + 1) * 4 + jt) * 512);
        }
        half8 b[8];
        #pragma unroll
        for (int mt = 0; mt < 8; ++mt)
            b[mt] = *(const half8*)&Hs[mt * 16 + m_][kk + quad * 8];
        #pragma unroll
        for (int jt = 0; jt < 4; ++jt)
            #pragma unroll
            for (int mt = 0; mt < 8; ++mt)
                acc[jt][mt] = __builtin_amdgcn_mfma_f32_16x16x32_f16(
                    a[jt], b[mt], acc[jt][mt], 0, 0, 0);
        if (kk + 32 < K) {
            #pragma unroll
            for (int jt = 0; jt < 4; ++jt) a[jt] = a2[jt];
        }
    }
    __syncthreads();   // all waves done reading Hs

    #pragma unroll
    for (int jt = 0; jt < 4; ++jt) {
        const int jbase = jb0 + jt * 16;
        #pragma unroll
        for (int mt = 0; mt < 8; ++mt) {
            const int node = mt * 16 + m_;
            const float ev = es[node];
            half4v h;
            h[0] = (_Float16)fmaxf(acc[jt][mt][0] + ev * w4[jt].x + bb[jt].x, 0.f);
            h[1] = (_Float16)fmaxf(acc[jt][mt][1] + ev * w4[jt].y + bb[jt].y, 0.f);
            h[2] = (_Float16)fmaxf(acc[jt][mt][2] + ev * w4[jt].z + bb[jt].z, 0.f);
            h[3] = (_Float16)fmaxf(acc[jt][mt][3] + ev * w4[jt].w + bb[jt].w, 0.f);
            *(half4v*)&Hs[node][jbase] = h;
        }
    }
    __syncthreads();   // Hs writes visible before next layer
}

// ---------------------------------------------------------------------------
// (256,2) kept: VGPR-128 + spill is the A/B-proven champion config (R0
// 159-170 us). R4 proved the spill is NOT the bottleneck (removing it
// regressed to 254 us). Do not "fix" the spill; do not shrink the wave tile.
__global__ __launch_bounds__(256, 2) void sage_fused(
    const float* __restrict__ node_feat,
    const int* __restrict__ cursor, const unsigned* __restrict__ pairs,
    const float* __restrict__ esh, int nsh,
    const _Float16* __restrict__ Wpack, const float* __restrict__ park,
    float* __restrict__ out) {

    __shared__ _Float16 Hs[128][264];   // +8-half pad
    __shared__ float esp[528];          // 4 shadows @ stride 132 (bank 4s+n)
    __shared__ float es[128];           // combined aggregate
    __shared__ float wf[256];
    __shared__ float red[2][128];

    const int tid  = threadIdx.x;
    const int wave = tid >> 6;
    const int lane = tid & 63;
    const int m_   = lane & 15;
    const int quad = lane >> 4;
    const int node0 = blockIdx.x * 128;

    for (int i = tid; i < 528; i += 256) esp[i] = 0.f;

    // hoist the gating cursor load: latency hides under the staging loop
    int cnt = 0;
    if (nsh == 0) cnt = min(cursor[blockIdx.x], CAP);
    __syncthreads();

    // ---- stage node_feat tile (fp32 -> fp16) ----
    for (int idx = tid; idx < 128 * 16; idx += 256) {
        const int row = idx >> 4, g = idx & 15;
        int node = node0 + row; if (node >= N_NODES) node = N_NODES - 1;
        const float4* src = (const float4*)(node_feat + (size_t)node * 128 + g * 8);
        const float4 v0 = src[0], v1 = src[1];
        half8 h;
        h[0] = (_Float16)v0.x; h[1] = (_Float16)v0.y;
        h[2] = (_Float16)v0.z; h[3] = (_Float16)v0.w;
        h[4] = (_Float16)v1.x; h[5] = (_Float16)v1.y;
        h[6] = (_Float16)v1.z; h[7] = (_Float16)v1.w;
        *(half8*)&Hs[row][g * 8] = h;
    }
    // ---- edge aggregate for this 128-node tile (1:1 bucket) ----
    if (nsh == 0) {
        const unsigned* __restrict__ pp = pairs + (size_t)blockIdx.x * CAP;
        const int sh = (tid & 3) * 132;
        for (int i = tid; i < cnt; i += 256) {
            const unsigned p = pp[i];
            atomicAdd(&esp[sh + (p & 127u)], __uint_as_float(p & 0xFFFFFF00u));
        }
    } else if (tid < 128) {
        int node = node0 + tid; if (node >= N_NODES) node = N_NODES - 1;
        float s = 0.f;
        for (int sh = 0; sh < nsh; ++sh) s += esh[(size_t)sh * SH_STRIDE + node];
        esp[tid] = s;
    }
    __syncthreads();
    if (tid < 128)
        es[tid] = esp[tid] + esp[132 + tid] + esp[264 + tid] + esp[396 + tid];
    __syncthreads();

    // layer 0: K=128; layers 1..6: K=256 (in-place Hs, 2 barriers each)
    layer_mm<128>(Wpack, Hs, es, park, wave, lane, m_, quad);
    for (int l = 1; l < 7; ++l)
        layer_mm<256>(Wpack + 32768 + (l - 1) * 65536, Hs, es, park + l * 512,
                      wave, lane, m_, quad);

    // ---- final 256 -> 1 dot (fp32, b128-vectorized LDS reads) ----
    wf[tid] = park[3584 + tid];
    __syncthreads();
    {
        const int row = tid & 127, seg = tid >> 7;
        const _Float16* hp = &Hs[row][seg * 128];
        const float* wpt = &wf[seg * 128];
        float s = 0.f;
        #pragma unroll
        for (int k = 0; k < 16; ++k) {
            const half8 h = *(const half8*)(hp + k * 8);
            const float* w8 = wpt + k * 8;
            s += (float)h[0] * w8[0] + (float)h[1] * w8[1]
               + (float)h[2] * w8[2] + (float)h[3] * w8[3]
               + (float)h[4] * w8[4] + (float)h[5] * w8[5]
               + (float)h[6] * w8[6] + (float)h[7] * w8[7];
        }
        red[seg][row] = s;
    }
    __syncthreads();
    if (tid < 128) {
        const int node = node0 + tid;
        if (node < N_NODES)
            out[node] = red[0][tid] + red[1][tid] + park[3840];
    }
}

// ---------------------------------------------------------------------------
extern "C" void kernel_launch(void* const* d_in, const int* in_sizes, int n_in,
                              void* d_out, int out_size, void* d_ws,
                              size_t ws_size, hipStream_t stream) {
    const float* node_feat = (const float*)d_in[0];
    const float* edge_feat = (const float*)d_in[1];
    const int*   edge_dst  = (const int*)d_in[2];
    const float* W1  = (const float*)d_in[3];  const float* b1  = (const float*)d_in[4];
    const float* Wm1 = (const float*)d_in[5];  const float* bm1 = (const float*)d_in[6];
    const float* Wm2 = (const float*)d_in[7];  const float* bm2 = (const float*)d_in[8];
    const float* Wm3 = (const float*)d_in[9];  const float* bm3 = (const float*)d_in[10];
    const float* Wm4 = (const float*)d_in[11]; const float* bm4 = (const float*)d_in[12];
    const float* Wr1 = (const float*)d_in[13]; const float* br1 = (const float*)d_in[14];
    const float* Wr2 = (const float*)d_in[15]; const float* br2 = (const float*)d_in[16];
    const float* Wr3 = (const float*)d_in[17]; const float* br3 = (const float*)d_in[18];
    float* out = (float*)d_out;

    // ws layout: cursor | Wp | park | pairs (fallback: esh over pairs)
    char* ws = (char*)d_ws;
    int*      cursor = (int*)ws;                           // 4096 B reserved
    _Float16* Wp     = (_Float16*)(ws + 4096);             // 851968 B
    float*    park   = (float*)(ws + 856064);              // 16384 B
    unsigned* pairs  = (unsigned*)(ws + 872448);           // NBUCK*CAP*4 B
    float*    esh    = (float*)(ws + 872448);              // fallback shadows

    const size_t need_bins = 872448 + (size_t)NBUCK * CAP * 4;   // ~16.9 MB
    const bool use_bins = (ws_size >= need_bins);

    const int nblk = (N_NODES + 127) / 128;   // 782

    if (use_bins) {
        hipMemsetAsync(cursor, 0, NBUCK * sizeof(int), stream);
        binpack<<<NBIN + NPK, 512, 0, stream>>>(
            edge_feat, edge_dst, W1, Wm1, Wm2, Wm3, Wm4, Wr1, Wr2,
            b1, bm1, bm2, bm3, bm4, br1, br2, Wr3, br3,
            cursor, pairs, Wp, park, 1);
        sage_fused<<<nblk, 256, 0, stream>>>(node_feat, cursor, pairs,
                                             nullptr, 0, Wp, park, out);
    } else {
        binpack<<<NPK, 512, 0, stream>>>(
            edge_feat, edge_dst, W1, Wm1, Wm2, Wm3, Wm4, Wr1, Wr2,
            b1, bm1, bm2, bm3, bm4, br1, br2, Wr3, br3,
            cursor, pairs, Wp, park, 0);
        hipMemsetAsync(esh, 0, (size_t)4 * SH_STRIDE * 4, stream);
        scatter4<<<3125, 256, 0, stream>>>((const float4*)edge_feat,
                                           (const int4*)edge_dst, esh);
        sage_fused<<<nblk, 256, 0, stream>>>(node_feat, nullptr, nullptr,
                                             esh, 4, Wp, park, out);
    }
}